// Round 1
// baseline (158.045 us; speedup 1.0000x reference)
//
#include <hip/hip_runtime.h>
#include <hip/hip_bf16.h>
#include <math.h>

#define BATCH 16
#define SEQ   2048
#define HID   128
#define DIM   64
#define QCH   4      // q-chunks per (b, kblock) for the attention sweep

typedef __attribute__((ext_vector_type(8))) short bf16x8;
typedef __attribute__((ext_vector_type(4))) float f32x4;

// 0.125 (1/sqrt(D)) * log2(e): folded into Wq so MFMA emits log2-domain scores
#define QSCALE 0.18033688011112042f
#define C0_PE  0.07195578314043169f   // ln(10000)/128

static __device__ __forceinline__ ushort f2bf(float f) {
    union { float f; unsigned u; } v; v.f = f;
    unsigned r = v.u + 0x7FFFu + ((v.u >> 16) & 1u);   // RNE
    return (ushort)(r >> 16);
}

static __device__ __forceinline__ float fast_exp2(float x) {
#if __has_builtin(__builtin_amdgcn_exp2f)
    return __builtin_amdgcn_exp2f(x);
#else
    return exp2f(x);
#endif
}

// ---------------------------------------------------------------------------
// Prep: wvf[h] = Wv[h,:]·Wf  and  Wt[col][k] = bf16 of [Wq*QSCALE | Wk]^T
// ---------------------------------------------------------------------------
__global__ void k_prep(const float* __restrict__ Wq, const float* __restrict__ Wk,
                       const float* __restrict__ Wv, const float* __restrict__ Wf,
                       ushort* __restrict__ Wt, float* __restrict__ wvf) {
    const int tid = threadIdx.x;
    if (tid < HID) {
        float s = 0.f;
        #pragma unroll 8
        for (int d = 0; d < DIM; ++d) s += Wv[tid * DIM + d] * Wf[d];
        wvf[tid] = s;
    }
    for (int i = tid; i < 128 * 128; i += 256) {
        int col = i >> 7, k = i & 127;
        float v = (col < 64) ? Wq[k * DIM + col] * QSCALE : Wk[k * DIM + (col - 64)];
        Wt[i] = f2bf(v);
    }
}

// ---------------------------------------------------------------------------
// QKV (MFMA, no LDS): block = 64 rows, wave = 16 rows (R4-proven version).
// ---------------------------------------------------------------------------
__global__ __launch_bounds__(256) void k_qkv(
    const float* __restrict__ x, const ushort* __restrict__ Wt,
    const float* __restrict__ wvf, ushort* __restrict__ Qb,
    ushort* __restrict__ Kb, float* __restrict__ vf)
{
    const int tid  = threadIdx.x;
    const int wave = tid >> 6;
    const int lane = tid & 63;
    const int quad = lane >> 4;
    const int col  = lane & 15;
    const int rowbase = blockIdx.x * 64 + wave * 16;
    const int grow = rowbase + col;          // this lane's xp row (A m-index)
    const float pos = (float)(grow & (SEQ - 1));

    // ---- build A fragments (4 chunks of k=32) + vf partial ----
    bf16x8 af[4];
    float vpart = 0.f;
    #pragma unroll
    for (int c = 0; c < 4; ++c) {
        const float* xp = x + (size_t)grow * HID + quad * 8 + c * 32;
        float4 v0 = *(const float4*)(xp);
        float4 v1 = *(const float4*)(xp + 4);
        float t[8] = {v0.x, v0.y, v0.z, v0.w, v1.x, v1.y, v1.z, v1.w};
        #pragma unroll
        for (int jp = 0; jp < 4; ++jp) {
            int h = quad * 8 + c * 32 + jp * 2;      // even
            float ang = pos * __expf(-(float)h * C0_PE);
            t[jp * 2]     += __sinf(ang);
            t[jp * 2 + 1] += __cosf(ang);
        }
        const float* wp = wvf + quad * 8 + c * 32;
        float4 w0 = *(const float4*)(wp);
        float4 w1 = *(const float4*)(wp + 4);
        vpart += t[0] * w0.x + t[1] * w0.y + t[2] * w0.z + t[3] * w0.w +
                 t[4] * w1.x + t[5] * w1.y + t[6] * w1.z + t[7] * w1.w;
        short* ap = (short*)&af[c];
        #pragma unroll
        for (int j = 0; j < 8; ++j) ap[j] = (short)f2bf(t[j]);
    }

    vpart += __shfl_xor(vpart, 16);
    vpart += __shfl_xor(vpart, 32);
    if (quad == 0) vf[grow] = vpart;

    // ---- 8 col tiles: 0..3 -> Q (prescaled), 4..7 -> K ----
    #pragma unroll
    for (int t = 0; t < 8; ++t) {
        const ushort* wrow = Wt + (size_t)(t * 16 + col) * 128 + quad * 8;
        f32x4 acc = {0.f, 0.f, 0.f, 0.f};
        #pragma unroll
        for (int c = 0; c < 4; ++c) {
            bf16x8 bfr = *(const bf16x8*)(wrow + c * 32);
            acc = __builtin_amdgcn_mfma_f32_16x16x32_bf16(af[c], bfr, acc, 0, 0, 0);
        }
        // C layout: col = lane&15, row = quad*4 + r
        const int cb = (t & 3) * 16 + col;
        ushort* dst = (t < 4) ? Qb : Kb;
        const int r0 = rowbase + quad * 4;
        #pragma unroll
        for (int r = 0; r < 4; ++r)
            dst[(size_t)(r0 + r) * DIM + cb] = f2bf(acc[r]);
    }
}

// ---------------------------------------------------------------------------
// Attention pass 1: partial column sums.
// Block = (kblock of 64 cols, b, q-chunk of SEQ/QCH rows), 256 threads = 4 waves.
// Each wave sweeps 128 q-rows (8 qi of 16). Writes lpart[qc][b][k] once
// (no atomics, no zero-init needed: every slot written exactly once).
// ---------------------------------------------------------------------------
__global__ __launch_bounds__(256, 6) void k_colsum(
    const ushort* __restrict__ Qb, const ushort* __restrict__ Kb,
    float* __restrict__ lpart)
{
    const int b    = blockIdx.y;
    const int k0   = blockIdx.x * 64;
    const int qc   = blockIdx.z;
    const int tid  = threadIdx.x;
    const int wave = tid >> 6;
    const int lane = tid & 63;
    const int quad = lane >> 4;
    const int col  = lane & 15;

    __shared__ float sl[4][64];

    // resident K fragments: 4 tiles x 2 chunks
    bf16x8 kf[4][2];
    {
        const ushort* Kbase = Kb + ((size_t)(b * SEQ + k0)) * DIM;
        #pragma unroll
        for (int t = 0; t < 4; ++t)
            #pragma unroll
            for (int c = 0; c < 2; ++c)
                kf[t][c] = *(const bf16x8*)(Kbase + (size_t)(t * 16 + col) * DIM + quad * 8 + c * 32);
    }

    const ushort* Qrow = Qb +
        ((size_t)(b * SEQ + qc * (SEQ / QCH) + wave * 128 + col)) * DIM + quad * 8;

    float l[4] = {0.f, 0.f, 0.f, 0.f};
    for (int qi = 0; qi < 8; ++qi) {
        bf16x8 a0 = *(const bf16x8*)(Qrow);
        bf16x8 a1 = *(const bf16x8*)(Qrow + 32);
        Qrow += 16 * DIM;
        #pragma unroll
        for (int t = 0; t < 4; ++t) {
            f32x4 acc = {0.f, 0.f, 0.f, 0.f};
            acc = __builtin_amdgcn_mfma_f32_16x16x32_bf16(a0, kf[t][0], acc, 0, 0, 0);
            acc = __builtin_amdgcn_mfma_f32_16x16x32_bf16(a1, kf[t][1], acc, 0, 0, 0);
            l[t] += fast_exp2(acc.x) + fast_exp2(acc.y) +
                    fast_exp2(acc.z) + fast_exp2(acc.w);
        }
    }
    #pragma unroll
    for (int t = 0; t < 4; ++t) {
        l[t] += __shfl_xor(l[t], 16);
        l[t] += __shfl_xor(l[t], 32);
    }
    if (quad == 0) {
        #pragma unroll
        for (int t = 0; t < 4; ++t) sl[wave][t * 16 + col] = l[t];
    }
    __syncthreads();
    if (tid < 64) {
        float ll = sl[0][tid] + sl[1][tid] + sl[2][tid] + sl[3][tid];
        lpart[((size_t)qc * BATCH + b) * SEQ + k0 + tid] = ll;
    }
}

// ---------------------------------------------------------------------------
// Attention pass 2: weighted row sums -> atomic accumulate.
// Same decomposition as k_colsum. Prologue folds the QCH partial column
// sums into wcol = vf / l; each row receives exactly SEQ/64 = 32 atomic
// adds (one per kblock), so bias is folded as bf/32 per add.
// ---------------------------------------------------------------------------
__global__ __launch_bounds__(256, 6) void k_rowsum(
    const ushort* __restrict__ Qb, const ushort* __restrict__ Kb,
    const float* __restrict__ vf, const float* __restrict__ lpart,
    const float* __restrict__ bfp, float* __restrict__ outp)
{
    const int b    = blockIdx.y;
    const int k0   = blockIdx.x * 64;
    const int qc   = blockIdx.z;
    const int tid  = threadIdx.x;
    const int wave = tid >> 6;
    const int lane = tid & 63;
    const int quad = lane >> 4;
    const int col  = lane & 15;

    __shared__ float wcol[64];

    // resident K fragments (issued before the barrier so the wcol loads overlap)
    bf16x8 kf[4][2];
    {
        const ushort* Kbase = Kb + ((size_t)(b * SEQ + k0)) * DIM;
        #pragma unroll
        for (int t = 0; t < 4; ++t)
            #pragma unroll
            for (int c = 0; c < 2; ++c)
                kf[t][c] = *(const bf16x8*)(Kbase + (size_t)(t * 16 + col) * DIM + quad * 8 + c * 32);
    }

    if (tid < 64) {
        float ll = 0.f;
        #pragma unroll
        for (int q = 0; q < QCH; ++q)
            ll += lpart[((size_t)q * BATCH + b) * SEQ + k0 + tid];
        wcol[tid] = vf[(size_t)b * SEQ + k0 + tid] / ll;
    }
    __syncthreads();

    const float bias = bfp[0] * (1.0f / (SEQ / 64));   // each kblock adds bf/32
    float wreg[4];
    #pragma unroll
    for (int t = 0; t < 4; ++t) wreg[t] = wcol[t * 16 + col];

    const ushort* Qrow = Qb +
        ((size_t)(b * SEQ + qc * (SEQ / QCH) + wave * 128 + col)) * DIM + quad * 8;
    float* outb = outp + (size_t)b * SEQ;

    for (int qi = 0; qi < 8; ++qi) {
        bf16x8 a0 = *(const bf16x8*)(Qrow);
        bf16x8 a1 = *(const bf16x8*)(Qrow + 32);
        Qrow += 16 * DIM;
        float rs[4] = {0.f, 0.f, 0.f, 0.f};
        #pragma unroll
        for (int t = 0; t < 4; ++t) {
            f32x4 acc = {0.f, 0.f, 0.f, 0.f};
            acc = __builtin_amdgcn_mfma_f32_16x16x32_bf16(a0, kf[t][0], acc, 0, 0, 0);
            acc = __builtin_amdgcn_mfma_f32_16x16x32_bf16(a1, kf[t][1], acc, 0, 0, 0);
            #pragma unroll
            for (int r = 0; r < 4; ++r)
                rs[r] += fast_exp2(acc[r]) * wreg[t];
        }
        // reduce over the 16 k-cols (low 4 lane bits)
        #pragma unroll
        for (int r = 0; r < 4; ++r) {
            float v = rs[r];
            v += __shfl_xor(v, 1); v += __shfl_xor(v, 2);
            v += __shfl_xor(v, 4); v += __shfl_xor(v, 8);
            rs[r] = v;
        }
        if (col == 0) {
            const int qrow = qc * (SEQ / QCH) + wave * 128 + qi * 16 + quad * 4;
            #pragma unroll
            for (int r = 0; r < 4; ++r)
                atomicAdd(&outb[qrow + r], rs[r] + bias);
        }
    }
}

// ---------------------------------------------------------------------------
extern "C" void kernel_launch(void* const* d_in, const int* in_sizes, int n_in,
                              void* d_out, int out_size, void* d_ws, size_t ws_size,
                              hipStream_t stream) {
    (void)in_sizes; (void)n_in; (void)ws_size;
    const float* x  = (const float*)d_in[0];
    const float* Wq = (const float*)d_in[1];
    const float* Wk = (const float*)d_in[2];
    const float* Wv = (const float*)d_in[3];
    const float* Wf = (const float*)d_in[4];
    const float* bf = (const float*)d_in[5];
    float* outp = (float*)d_out;

    float*  wvf = (float*)d_ws;                                  // 256 floats
    float*  vf  = wvf + 256;                                     // B*S
    ushort* Wt  = (ushort*)(vf + (size_t)BATCH * SEQ);           // 128*128
    ushort* Qb  = Wt + 128 * 128;                                // B*S*D bf16
    ushort* Kb  = Qb + (size_t)BATCH * SEQ * DIM;                // B*S*D bf16
    float*  lpart = (float*)(Kb + (size_t)BATCH * SEQ * DIM);    // QCH*B*S floats

    hipMemsetAsync(d_out, 0, (size_t)out_size * sizeof(float), stream);
    k_prep<<<1, 256, 0, stream>>>(Wq, Wk, Wv, Wf, Wt, wvf);
    k_qkv<<<BATCH * SEQ / 64, 256, 0, stream>>>(x, Wt, wvf, Qb, Kb, vf);
    k_colsum<<<dim3(SEQ / 64, BATCH, QCH), 256, 0, stream>>>(Qb, Kb, lpart);
    k_rowsum<<<dim3(SEQ / 64, BATCH, QCH), 256, 0, stream>>>(Qb, Kb, vf, lpart, bf, outp);
}

// Round 2
// 130.798 us; speedup vs baseline: 1.2083x; 1.2083x over previous
//
#include <hip/hip_runtime.h>
#include <hip/hip_bf16.h>
#include <math.h>

#define BATCH 16
#define SEQ   2048
#define HID   128
#define DIM   64

typedef __attribute__((ext_vector_type(8))) short bf16x8;
typedef __attribute__((ext_vector_type(4))) float f32x4;

// 0.125 (1/sqrt(D)) * log2(e): folded into Wq so MFMA emits log2-domain scores
#define QSCALE 0.18033688011112042f
#define C0_PE  0.07195578314043169f   // ln(10000)/128

static __device__ __forceinline__ ushort f2bf(float f) {
    union { float f; unsigned u; } v; v.f = f;
    unsigned r = v.u + 0x7FFFu + ((v.u >> 16) & 1u);   // RNE
    return (ushort)(r >> 16);
}

static __device__ __forceinline__ float fast_exp2(float x) {
#if __has_builtin(__builtin_amdgcn_exp2f)
    return __builtin_amdgcn_exp2f(x);
#else
    return exp2f(x);
#endif
}

// ---------------------------------------------------------------------------
// Prep (parallel, 64 blocks): wvf[h] = Wv[h,:]·Wf  and
// Wt[col][k] = bf16 of [Wq*QSCALE | Wk]^T  (one element per thread).
// ---------------------------------------------------------------------------
__global__ __launch_bounds__(256) void k_prep(
    const float* __restrict__ Wq, const float* __restrict__ Wk,
    const float* __restrict__ Wv, const float* __restrict__ Wf,
    ushort* __restrict__ Wt, float* __restrict__ wvf) {
    const int gid = blockIdx.x * 256 + threadIdx.x;
    if (gid < HID) {
        float s = 0.f;
        #pragma unroll 8
        for (int d = 0; d < DIM; ++d) s += Wv[gid * DIM + d] * Wf[d];
        wvf[gid] = s;
    }
    if (gid < 128 * 128) {
        int col = gid >> 7, k = gid & 127;
        float v = (col < 64) ? Wq[k * DIM + col] * QSCALE : Wk[k * DIM + (col - 64)];
        Wt[gid] = f2bf(v);
    }
}

// ---------------------------------------------------------------------------
// QKV (MFMA, no LDS): block = 64 rows, wave = 16 rows (R4-proven version).
// ---------------------------------------------------------------------------
__global__ __launch_bounds__(256) void k_qkv(
    const float* __restrict__ x, const ushort* __restrict__ Wt,
    const float* __restrict__ wvf, ushort* __restrict__ Qb,
    ushort* __restrict__ Kb, float* __restrict__ vf)
{
    const int tid  = threadIdx.x;
    const int wave = tid >> 6;
    const int lane = tid & 63;
    const int quad = lane >> 4;
    const int col  = lane & 15;
    const int rowbase = blockIdx.x * 64 + wave * 16;
    const int grow = rowbase + col;          // this lane's xp row (A m-index)
    const float pos = (float)(grow & (SEQ - 1));

    // ---- build A fragments (4 chunks of k=32) + vf partial ----
    bf16x8 af[4];
    float vpart = 0.f;
    #pragma unroll
    for (int c = 0; c < 4; ++c) {
        const float* xp = x + (size_t)grow * HID + quad * 8 + c * 32;
        float4 v0 = *(const float4*)(xp);
        float4 v1 = *(const float4*)(xp + 4);
        float t[8] = {v0.x, v0.y, v0.z, v0.w, v1.x, v1.y, v1.z, v1.w};
        #pragma unroll
        for (int jp = 0; jp < 4; ++jp) {
            int h = quad * 8 + c * 32 + jp * 2;      // even
            float ang = pos * __expf(-(float)h * C0_PE);
            t[jp * 2]     += __sinf(ang);
            t[jp * 2 + 1] += __cosf(ang);
        }
        const float* wp = wvf + quad * 8 + c * 32;
        float4 w0 = *(const float4*)(wp);
        float4 w1 = *(const float4*)(wp + 4);
        vpart += t[0] * w0.x + t[1] * w0.y + t[2] * w0.z + t[3] * w0.w +
                 t[4] * w1.x + t[5] * w1.y + t[6] * w1.z + t[7] * w1.w;
        short* ap = (short*)&af[c];
        #pragma unroll
        for (int j = 0; j < 8; ++j) ap[j] = (short)f2bf(t[j]);
    }

    vpart += __shfl_xor(vpart, 16);
    vpart += __shfl_xor(vpart, 32);
    if (quad == 0) vf[grow] = vpart;

    // ---- 8 col tiles: 0..3 -> Q (prescaled), 4..7 -> K ----
    #pragma unroll
    for (int t = 0; t < 8; ++t) {
        const ushort* wrow = Wt + (size_t)(t * 16 + col) * 128 + quad * 8;
        f32x4 acc = {0.f, 0.f, 0.f, 0.f};
        #pragma unroll
        for (int c = 0; c < 4; ++c) {
            bf16x8 bfr = *(const bf16x8*)(wrow + c * 32);
            acc = __builtin_amdgcn_mfma_f32_16x16x32_bf16(af[c], bfr, acc, 0, 0, 0);
        }
        // C layout: col = lane&15, row = quad*4 + r
        const int cb = (t & 3) * 16 + col;
        ushort* dst = (t < 4) ? Qb : Kb;
        const int r0 = rowbase + quad * 4;
        #pragma unroll
        for (int r = 0; r < 4; ++r)
            dst[(size_t)(r0 + r) * DIM + cb] = f2bf(acc[r]);
    }
}

// ---------------------------------------------------------------------------
// Fused attention (MFMA): block = (b, 64 k-cols), 1024 threads = 16 waves.
// Grid = 512 blocks -> 2 blocks/CU x 32 waves/CU = 100% occupancy cap
// (round-0's 8-wave blocks left the machine half empty: 4096/8192 waves).
// Phase A: waves jointly sweep all 2048 q rows (128 rows each) -> full
//          column sums l for this block's 64 columns -> wcol = vf/l in LDS.
// Phase B: re-sweep q; rs[row] += exp2(s)*wcol; per-row shuffle reduce;
//          one atomicAdd per (block,row) with bias/32 folded in.
// ---------------------------------------------------------------------------
__global__ __launch_bounds__(1024) void k_attn(
    const ushort* __restrict__ Qb, const ushort* __restrict__ Kb,
    const float* __restrict__ vf, const float* __restrict__ bfp,
    float* __restrict__ outp)
{
    const int b    = blockIdx.y;
    const int k0   = blockIdx.x * 64;
    const int tid  = threadIdx.x;
    const int wave = tid >> 6;
    const int lane = tid & 63;
    const int quad = lane >> 4;
    const int col  = lane & 15;

    __shared__ float sl[16][64];
    __shared__ float wcol[64];

    // resident K fragments: 4 tiles x 2 chunks
    bf16x8 kf[4][2];
    {
        const ushort* Kbase = Kb + ((size_t)(b * SEQ + k0)) * DIM;
        #pragma unroll
        for (int t = 0; t < 4; ++t)
            #pragma unroll
            for (int c = 0; c < 2; ++c)
                kf[t][c] = *(const bf16x8*)(Kbase + (size_t)(t * 16 + col) * DIM + quad * 8 + c * 32);
    }

    const ushort* Qstart = Qb + ((size_t)(b * SEQ + wave * 128 + col)) * DIM + quad * 8;

    // ---- Phase A: column sums (each wave: 128 q rows = 8 tiles of 16) ----
    float l[4] = {0.f, 0.f, 0.f, 0.f};
    {
        const ushort* Qrow = Qstart;
        for (int qi = 0; qi < 8; ++qi) {
            bf16x8 a0 = *(const bf16x8*)(Qrow);
            bf16x8 a1 = *(const bf16x8*)(Qrow + 32);
            Qrow += 16 * DIM;
            #pragma unroll
            for (int t = 0; t < 4; ++t) {
                f32x4 acc = {0.f, 0.f, 0.f, 0.f};
                acc = __builtin_amdgcn_mfma_f32_16x16x32_bf16(a0, kf[t][0], acc, 0, 0, 0);
                acc = __builtin_amdgcn_mfma_f32_16x16x32_bf16(a1, kf[t][1], acc, 0, 0, 0);
                l[t] += fast_exp2(acc.x) + fast_exp2(acc.y) +
                        fast_exp2(acc.z) + fast_exp2(acc.w);
            }
        }
    }
    #pragma unroll
    for (int t = 0; t < 4; ++t) {
        l[t] += __shfl_xor(l[t], 16);
        l[t] += __shfl_xor(l[t], 32);
    }
    if (quad == 0) {
        #pragma unroll
        for (int t = 0; t < 4; ++t) sl[wave][t * 16 + col] = l[t];
    }
    __syncthreads();
    if (tid < 64) {
        float ll = 0.f;
        #pragma unroll
        for (int w = 0; w < 16; ++w) ll += sl[w][tid];
        wcol[tid] = vf[(size_t)b * SEQ + k0 + tid] / ll;
    }
    __syncthreads();

    // ---- Phase B: weighted row sums -> atomic accumulate ----
    const float bias = bfp[0] * (1.0f / (SEQ / 64));   // each block adds bf/32
    float wreg[4];
    #pragma unroll
    for (int t = 0; t < 4; ++t) wreg[t] = wcol[t * 16 + col];

    {
        const ushort* Qrow = Qstart;
        float* outb = outp + (size_t)b * SEQ;
        for (int qi = 0; qi < 8; ++qi) {
            bf16x8 a0 = *(const bf16x8*)(Qrow);
            bf16x8 a1 = *(const bf16x8*)(Qrow + 32);
            Qrow += 16 * DIM;
            float rs[4] = {0.f, 0.f, 0.f, 0.f};
            #pragma unroll
            for (int t = 0; t < 4; ++t) {
                f32x4 acc = {0.f, 0.f, 0.f, 0.f};
                acc = __builtin_amdgcn_mfma_f32_16x16x32_bf16(a0, kf[t][0], acc, 0, 0, 0);
                acc = __builtin_amdgcn_mfma_f32_16x16x32_bf16(a1, kf[t][1], acc, 0, 0, 0);
                #pragma unroll
                for (int r = 0; r < 4; ++r)
                    rs[r] += fast_exp2(acc[r]) * wreg[t];
            }
            // reduce over the 16 k-cols (low 4 lane bits)
            #pragma unroll
            for (int r = 0; r < 4; ++r) {
                float v = rs[r];
                v += __shfl_xor(v, 1); v += __shfl_xor(v, 2);
                v += __shfl_xor(v, 4); v += __shfl_xor(v, 8);
                rs[r] = v;
            }
            if (col == 0) {
                const int qrow = wave * 128 + qi * 16 + quad * 4;
                #pragma unroll
                for (int r = 0; r < 4; ++r)
                    atomicAdd(&outb[qrow + r], rs[r] + bias);
            }
        }
    }
}

// ---------------------------------------------------------------------------
extern "C" void kernel_launch(void* const* d_in, const int* in_sizes, int n_in,
                              void* d_out, int out_size, void* d_ws, size_t ws_size,
                              hipStream_t stream) {
    (void)in_sizes; (void)n_in; (void)ws_size;
    const float* x  = (const float*)d_in[0];
    const float* Wq = (const float*)d_in[1];
    const float* Wk = (const float*)d_in[2];
    const float* Wv = (const float*)d_in[3];
    const float* Wf = (const float*)d_in[4];
    const float* bf = (const float*)d_in[5];
    float* outp = (float*)d_out;

    float*  wvf = (float*)d_ws;                                  // 256 floats
    float*  vf  = wvf + 256;                                     // B*S
    ushort* Wt  = (ushort*)(vf + (size_t)BATCH * SEQ);           // 128*128
    ushort* Qb  = Wt + 128 * 128;                                // B*S*D bf16
    ushort* Kb  = Qb + (size_t)BATCH * SEQ * DIM;                // B*S*D bf16

    hipMemsetAsync(d_out, 0, (size_t)out_size * sizeof(float), stream);
    k_prep<<<64, 256, 0, stream>>>(Wq, Wk, Wv, Wf, Wt, wvf);
    k_qkv<<<BATCH * SEQ / 64, 256, 0, stream>>>(x, Wt, wvf, Qb, Kb, vf);
    k_attn<<<dim3(SEQ / 64, BATCH), 1024, 0, stream>>>(Qb, Kb, vf, bf, outp);
}